// Round 9
// baseline (534.807 us; speedup 1.0000x reference)
//
#include <hip/hip_runtime.h>

#define N_NODES 50000
#define N_EDGES 800000
#define FDIM 128
#define NROWS 100000   // B * N_NODES
#define BN_EPS 1e-5f
#define SCAN_BLOCKS 196   // ceil(50000 / 256)

typedef unsigned short ushort_t;
typedef unsigned int uint_t;
typedef __attribute__((ext_vector_type(8))) short bf16x8;   // MFMA A/B frag
typedef __attribute__((ext_vector_type(4))) float f32x4;    // MFMA C/D frag

// round-to-nearest-even fp32 -> bf16
__device__ inline ushort_t f2bf(float f) {
    uint_t x = __float_as_uint(f);
    x += 0x7fffu + ((x >> 16) & 1u);
    return (ushort_t)(x >> 16);
}
__device__ inline float4 bf4_to_f4(ushort4 u) {
    float4 f;
    f.x = __uint_as_float((uint_t)u.x << 16);
    f.y = __uint_as_float((uint_t)u.y << 16);
    f.z = __uint_as_float((uint_t)u.z << 16);
    f.w = __uint_as_float((uint_t)u.w << 16);
    return f;
}
// split-bf16: f = hi + lo with |err| ~ 2^-18 |f|
__device__ inline void split4(float4 v, bf16x8& hi, bf16x8& lo, int base) {
    float f[4] = {v.x, v.y, v.z, v.w};
    #pragma unroll
    for (int t = 0; t < 4; ++t) {
        ushort_t h = f2bf(f[t]);
        float fh = __uint_as_float((uint_t)h << 16);
        ushort_t l = f2bf(f[t] - fh);
        hi[base + t] = (short)h;
        lo[base + t] = (short)l;
    }
}

// ---------------- CSR build (per-destination buckets) ----------------

__global__ __launch_bounds__(256) void hist_kernel(const int* __restrict__ col,
                                                   int* __restrict__ cnt) {
    int e = blockIdx.x * 256 + threadIdx.x;
    if (e < N_EDGES) atomicAdd(&cnt[col[e]], 1);
}

__global__ __launch_bounds__(256) void scan_partials_sum(const int* __restrict__ cnt,
                                                         int* __restrict__ partials) {
    __shared__ int ws[4];
    int tid = threadIdx.x, lane = tid & 63, wid = tid >> 6;
    int i = blockIdx.x * 256 + tid;
    int v = (i < N_NODES) ? cnt[i] : 0;
    #pragma unroll
    for (int d = 32; d > 0; d >>= 1) v += __shfl_xor(v, d);
    if (lane == 0) ws[wid] = v;
    __syncthreads();
    if (tid == 0) partials[blockIdx.x] = ws[0] + ws[1] + ws[2] + ws[3];
}

__global__ __launch_bounds__(256) void scan_partials_scan(int* __restrict__ partials,
                                                          int* __restrict__ offsets) {
    __shared__ int ws[4];
    int tid = threadIdx.x, lane = tid & 63, wid = tid >> 6;
    int v = (tid < SCAN_BLOCKS) ? partials[tid] : 0;
    int x = v;
    #pragma unroll
    for (int d = 1; d < 64; d <<= 1) {
        int y = __shfl_up(x, d);
        if (lane >= d) x += y;
    }
    if (lane == 63) ws[wid] = x;
    __syncthreads();
    int woff = 0;
    for (int w = 0; w < wid; ++w) woff += ws[w];
    if (tid < SCAN_BLOCKS) partials[tid] = woff + x - v;   // exclusive
    if (tid == 255) offsets[N_NODES] = woff + x;           // grand total
}

__global__ __launch_bounds__(256) void scan_final(const int* __restrict__ cnt,
                                                  const int* __restrict__ partials,
                                                  int* __restrict__ offsets,
                                                  int* __restrict__ cursor) {
    __shared__ int ws[4];
    int tid = threadIdx.x, lane = tid & 63, wid = tid >> 6;
    int i = blockIdx.x * 256 + tid;
    int v = (i < N_NODES) ? cnt[i] : 0;
    int x = v;
    #pragma unroll
    for (int d = 1; d < 64; d <<= 1) {
        int y = __shfl_up(x, d);
        if (lane >= d) x += y;
    }
    if (lane == 63) ws[wid] = x;
    __syncthreads();
    int woff = 0;
    for (int w = 0; w < wid; ++w) woff += ws[w];
    if (i < N_NODES) {
        int off = partials[blockIdx.x] + woff + x - v;
        offsets[i] = off;
        cursor[i] = off;
    }
}

__global__ __launch_bounds__(256) void bucket_kernel(const int* __restrict__ row,
                                                     const int* __restrict__ col,
                                                     int* __restrict__ cursor,
                                                     int* __restrict__ srcbuf) {
    int e = blockIdx.x * 256 + threadIdx.x;
    if (e < N_EDGES) {
        int c = col[e];
        int p = atomicAdd(&cursor[c], 1);
        srcbuf[p] = row[e];
    }
}

// ---------------- W pre-transform + workspace zeroing ----------------
__global__ __launch_bounds__(256) void wsplit_kernel(const float* __restrict__ W1,
                                                     const float* __restrict__ W2,
                                                     ushort_t* __restrict__ wt,
                                                     int* __restrict__ cnt,
                                                     float* __restrict__ stats) {
    int idx = blockIdx.x * 256 + threadIdx.x;   // 0..32767
    for (int i = idx; i < N_NODES; i += 32768) cnt[i] = 0;
    if (idx < 512) stats[idx] = 0.f;
    int which = idx >> 14;
    int e = idx & 16383;                         // e = k*128 + n (coalesced read)
    int k = e >> 7, n = e & 127;
    float f = (which ? W2 : W1)[e];
    ushort_t h = f2bf(f);
    float fh = __uint_as_float((uint_t)h << 16);
    ushort_t l = f2bf(f - fh);
    size_t base = (size_t)which * 32768;
    wt[base + n * 128 + k] = h;                  // hi plane
    wt[base + 16384 + n * 128 + k] = l;          // lo plane
}

// ---------------- GEMM via split-bf16 MFMA, A-only LDS, B direct from L2 ----------------
// C layout: interleaved sup [node][batch][128] bf16 (512B contiguous per node for the gather).
// LDS 33KB -> 4 blocks/CU. B-frag for (n, step s, quad q) = wt[n*128 + (s*4+q)*8] (L2-hot 64KB).
template <bool BN>
__global__ __launch_bounds__(256) void gemm_mfma(const float* __restrict__ A,
                                                 const ushort_t* __restrict__ wt,
                                                 const float* __restrict__ stats,
                                                 const float* __restrict__ gamma,
                                                 const float* __restrict__ beta,
                                                 ushort_t* __restrict__ C) {
    __shared__ short lds[16384];  // Ah[0,8192) Al[8192,16384)
    __shared__ float cs[256];     // scale[0:128], shift[128:256]
    int tid = threadIdx.x;
    long r0 = (long)blockIdx.x * 64;
    const float4* A4 = (const float4*)A;

    if (BN) {
        if (tid < 128) {
            float inv = 1.0f / (float)NROWS;
            float mean = stats[tid] * inv;
            float var = stats[128 + tid] * inv - mean * mean;
            float scale = gamma[tid] / sqrtf(var + BN_EPS);
            cs[tid] = scale;
            cs[128 + tid] = beta[tid] - mean * scale;
        }
        __syncthreads();
    }
    const float4* coef4 = (const float4*)cs;

    // stage A split: 1024 tasks of one 16B bf16 block (8 elems) each
    #pragma unroll
    for (int i = 0; i < 4; ++i) {
        int li = tid + i * 256;
        int r = li >> 4, j = li & 15;        // row 0..63, k-block 0..15
        long gr = r0 + r;
        float4 va = make_float4(0.f, 0.f, 0.f, 0.f), vb = va;
        if (gr < NROWS) { va = A4[gr * 32 + j * 2]; vb = A4[gr * 32 + j * 2 + 1]; }
        if (BN) {
            float4 sc = coef4[j * 2], sh = coef4[32 + j * 2];
            va.x = fmaxf(va.x * sc.x + sh.x, 0.f);
            va.y = fmaxf(va.y * sc.y + sh.y, 0.f);
            va.z = fmaxf(va.z * sc.z + sh.z, 0.f);
            va.w = fmaxf(va.w * sc.w + sh.w, 0.f);
            sc = coef4[j * 2 + 1]; sh = coef4[32 + j * 2 + 1];
            vb.x = fmaxf(vb.x * sc.x + sh.x, 0.f);
            vb.y = fmaxf(vb.y * sc.y + sh.y, 0.f);
            vb.z = fmaxf(vb.z * sc.z + sh.z, 0.f);
            vb.w = fmaxf(vb.w * sc.w + sh.w, 0.f);
        }
        bf16x8 vh, vl;
        split4(va, vh, vl, 0);
        split4(vb, vh, vl, 4);
        int off = r * 128 + ((j ^ (r & 15)) * 8);
        *(bf16x8*)&lds[off] = vh;
        *(bf16x8*)&lds[8192 + off] = vl;
    }
    __syncthreads();

    int w = tid >> 6, l = tid & 63;
    int m = l & 15, q = l >> 4;

    f32x4 acc[8] = {};
    #pragma unroll
    for (int s = 0; s < 4; ++s) {
        int x = (s * 4 + q) ^ m;
        int aoff = (w * 16 + m) * 128 + x * 8;
        bf16x8 ah = *(const bf16x8*)&lds[aoff];
        bf16x8 al = *(const bf16x8*)&lds[8192 + aoff];
        #pragma unroll
        for (int c = 0; c < 8; ++c) {
            const ushort_t* bp = wt + (c * 16 + m) * 128 + (s * 4 + q) * 8;
            bf16x8 bh = *(const bf16x8*)bp;
            bf16x8 bl = *(const bf16x8*)(bp + 16384);
            acc[c] = __builtin_amdgcn_mfma_f32_16x16x32_bf16(al, bh, acc[c], 0, 0, 0);
            acc[c] = __builtin_amdgcn_mfma_f32_16x16x32_bf16(ah, bl, acc[c], 0, 0, 0);
            acc[c] = __builtin_amdgcn_mfma_f32_16x16x32_bf16(ah, bh, acc[c], 0, 0, 0);
        }
    }

    // write C in interleaved layout: row gr -> (node*2 + b) * 128
    #pragma unroll
    for (int r = 0; r < 4; ++r) {
        long gr = r0 + w * 16 + q * 4 + r;
        if (gr < NROWS) {
            int b = gr >= N_NODES;
            long node = gr - (long)b * N_NODES;
            ushort_t* crow = C + (node * 2 + b) * 128 + m;
            #pragma unroll
            for (int c = 0; c < 8; ++c) crow[c * 16] = f2bf(acc[c][r]);
        }
    }
}

// ---------------- Aggregate (verified hot loop; interleaved sup rows) ----------------
// One wave per node, BOTH batches. Half-wave s handles edges j=2t+s; per edge the
// 512B interleaved row [batch0|batch1] is read as two adjacent 256B segments.
__global__ __launch_bounds__(256) void aggregate_bf16(const ushort_t* __restrict__ sup,
                                                      const int* __restrict__ offsets,
                                                      const int* __restrict__ srcbuf,
                                                      float* __restrict__ agg) {
    int lane = threadIdx.x & 63;
    int wid = threadIdx.x >> 6;
    int node = blockIdx.x * 4 + wid;        // 12500*4 = 50000 exactly
    int s = lane >> 5;       // half-wave id
    int l32 = lane & 31;
    int beg = offsets[node], end = offsets[node + 1];
    const ushort4* sb = (const ushort4*)sup;   // row r: [r*64, r*64+32)=batch0, +32..64)=batch1
    float4 a0 = make_float4(0.f, 0.f, 0.f, 0.f);
    float4 a1 = make_float4(0.f, 0.f, 0.f, 0.f);
    for (int i = beg; i < end; i += 64) {
        int m = end - i; if (m > 64) m = 64;
        int idx = (i + lane < end) ? srcbuf[i + lane] : 0;  // coalesced index load
        int tmax = (m + 1) >> 1;
        #pragma unroll 2
        for (int t = 0; t < tmax; ++t) {
            int j = 2 * t + s;
            int r = __shfl(idx, j & 63);
            ushort4 u0 = sb[(size_t)r * 64 + l32];        // batch 0 half-row
            ushort4 u1 = sb[(size_t)r * 64 + 32 + l32];   // batch 1 half-row
            if (j < m) {
                float4 f0 = bf4_to_f4(u0);
                float4 f1 = bf4_to_f4(u1);
                a0.x += f0.x; a0.y += f0.y; a0.z += f0.z; a0.w += f0.w;
                a1.x += f1.x; a1.y += f1.y; a1.z += f1.z; a1.w += f1.w;
            }
        }
    }
    a0.x += __shfl_xor(a0.x, 32); a0.y += __shfl_xor(a0.y, 32);
    a0.z += __shfl_xor(a0.z, 32); a0.w += __shfl_xor(a0.w, 32);
    a1.x += __shfl_xor(a1.x, 32); a1.y += __shfl_xor(a1.y, 32);
    a1.z += __shfl_xor(a1.z, 32); a1.w += __shfl_xor(a1.w, 32);
    float4* ag = (float4*)agg;
    if (s == 0) ag[(size_t)node * 32 + l32] = a0;                       // batch 0 row
    else        ag[(size_t)(N_NODES + node) * 32 + l32] = a1;           // batch 1 row
}

// ---------------- BatchNorm stats (over raw agg) ----------------

__global__ __launch_bounds__(256) void bn_stats_kernel(const float* __restrict__ h,
                                                       float* __restrict__ stats) {
    __shared__ float ls[256], ls2[256];
    int tid = threadIdx.x;
    int f = tid & 127, half = tid >> 7;
    float s = 0.f, s2 = 0.f;
    for (int row = blockIdx.x * 2 + half; row < NROWS; row += gridDim.x * 2) {
        float v = h[(size_t)row * FDIM + f];
        s += v; s2 += v * v;
    }
    ls[tid] = s; ls2[tid] = s2;
    __syncthreads();
    if (tid < 128) {
        atomicAdd(&stats[f], ls[tid] + ls[tid + 128]);
        atomicAdd(&stats[128 + f], ls2[tid] + ls2[tid + 128]);
    }
}

// ---------------- Layer 3: fused BN+ReLU GEMV (coef in-block) + CSR gather ----------------
__global__ __launch_bounds__(256) void gemv_bn_kernel(const float* __restrict__ h,
                                                      const float* __restrict__ stats,
                                                      const float* __restrict__ gamma,
                                                      const float* __restrict__ beta,
                                                      const float* __restrict__ W3,
                                                      float* __restrict__ sup3) {
    __shared__ float cs[256];
    int tid = threadIdx.x;
    if (tid < 128) {
        float inv = 1.0f / (float)NROWS;
        float mean = stats[tid] * inv;
        float var = stats[128 + tid] * inv - mean * mean;
        float scale = gamma[tid] / sqrtf(var + BN_EPS);
        cs[tid] = scale;
        cs[128 + tid] = beta[tid] - mean * scale;
    }
    __syncthreads();
    int lane = tid & 63, wid = tid >> 6;
    float2 w  = ((const float2*)W3)[lane];
    float2 sc = ((const float2*)cs)[lane];
    float2 sh = ((const float2*)(cs + 128))[lane];
    #pragma unroll
    for (int r = 0; r < 4; ++r) {
        long gw = (long)blockIdx.x * 16 + wid * 4 + r;   // 6250*16 = 100000 exactly
        float2 v = ((const float2*)h)[(size_t)gw * 64 + lane];
        v.x = fmaxf(v.x * sc.x + sh.x, 0.f);
        v.y = fmaxf(v.y * sc.y + sh.y, 0.f);
        float s = v.x * w.x + v.y * w.y;
        #pragma unroll
        for (int d = 32; d > 0; d >>= 1) s += __shfl_xor(s, d);
        if (lane == 0) sup3[gw] = s;
    }
}

// out[b,n] = b3 + sum over CSR in-edges of sup3[b, src].
__global__ __launch_bounds__(256) void gather_out_kernel(const int* __restrict__ offsets,
                                                         const int* __restrict__ srcbuf,
                                                         const float* __restrict__ sup3,
                                                         const float* __restrict__ b3,
                                                         float* __restrict__ out) {
    int n = blockIdx.x * 256 + threadIdx.x;
    if (n >= N_NODES) return;
    int beg = offsets[n], end = offsets[n + 1];
    float s0 = 0.f, s1 = 0.f;
    for (int i = beg; i < end; ++i) {
        int r = srcbuf[i];
        s0 += sup3[r];
        s1 += sup3[N_NODES + r];
    }
    float b = b3[0];
    out[n] = s0 + b;
    out[N_NODES + n] = s1 + b;
}

// ---------------- launch ----------------

extern "C" void kernel_launch(void* const* d_in, const int* in_sizes, int n_in,
                              void* d_out, int out_size, void* d_ws, size_t ws_size,
                              hipStream_t stream) {
    const float* x      = (const float*)d_in[0];
    const int*   ei     = (const int*)d_in[1];
    const float* W1     = (const float*)d_in[2];
    // d_in[3] = b1: per-feature bias before BN cancels exactly (shifts mean identically)
    const float* W2     = (const float*)d_in[4];
    // d_in[5] = b2: same cancellation
    const float* W3     = (const float*)d_in[6];
    const float* b3     = (const float*)d_in[7];
    const float* gamma1 = (const float*)d_in[8];
    const float* beta1  = (const float*)d_in[9];
    const float* gamma2 = (const float*)d_in[10];
    const float* beta2  = (const float*)d_in[11];
    const int* rowp = ei;             // edge_index[0]
    const int* colp = ei + N_EDGES;   // edge_index[1]

    ushort_t* sup   = (ushort_t*)d_ws;              // 12.8M bf16 (25.6 MB), [node][batch][128]
    float* agg      = (float*)(sup + 12800000);     // 12.8M floats (51.2 MB), [b*N+node][128]
    float* sup3     = agg + 12800000;               // 100k floats
    ushort_t* wt    = (ushort_t*)(sup3 + 100000);   // 65536 ushorts: W1/W2 split planes
    float* stats    = (float*)(wt + 65536);         // 512 floats
    int*   cnt      = (int*)(stats + 512);          // 50000
    int*   offsets  = cnt + N_NODES;                // 50001
    int*   cursor   = offsets + N_NODES + 1;        // 50000
    int*   srcbuf   = cursor + N_NODES;             // 800000
    int*   scanp    = srcbuf + N_EDGES;             // 196
    float* out      = (float*)d_out;

    // W split/transpose + cnt/stats zeroing, then CSR build
    wsplit_kernel     <<<128,         256, 0, stream>>>(W1, W2, wt, cnt, stats);
    hist_kernel       <<<3125,        256, 0, stream>>>(colp, cnt);
    scan_partials_sum <<<SCAN_BLOCKS, 256, 0, stream>>>(cnt, scanp);
    scan_partials_scan<<<1,           256, 0, stream>>>(scanp, offsets);
    scan_final        <<<SCAN_BLOCKS, 256, 0, stream>>>(cnt, scanp, offsets, cursor);
    bucket_kernel     <<<3125,        256, 0, stream>>>(rowp, colp, cursor, srcbuf);

    // layer 1: sup = x@W1 (split-bf16 MFMA), agg = A·sup, stats
    gemm_mfma<false><<<1563,  256, 0, stream>>>(x, wt, nullptr, nullptr, nullptr, sup);
    aggregate_bf16  <<<12500, 256, 0, stream>>>(sup, offsets, srcbuf, agg);
    bn_stats_kernel <<<512,   256, 0, stream>>>(agg, stats);

    // layer 2: sup = relu(bn1(agg))@W2 (coef computed in-block), agg = A·sup, stats
    gemm_mfma<true> <<<1563,  256, 0, stream>>>(agg, wt + 32768, stats, gamma1, beta1, sup);
    aggregate_bf16  <<<12500, 256, 0, stream>>>(sup, offsets, srcbuf, agg);
    bn_stats_kernel <<<512,   256, 0, stream>>>(agg, stats + 256);

    // layer 3: sup3 = relu(bn2(agg))@W3 (coef in-block), out = A·sup3 + b3 (CSR gather)
    gemv_bn_kernel   <<<6250, 256, 0, stream>>>(agg, stats + 256, gamma2, beta2, W3, sup3);
    gather_out_kernel<<<SCAN_BLOCKS, 256, 0, stream>>>(offsets, srcbuf, sup3, b3, out);
}

// Round 10
// 450.316 us; speedup vs baseline: 1.1876x; 1.1876x over previous
//
#include <hip/hip_runtime.h>

#define N_NODES 50000
#define N_EDGES 800000
#define FDIM 128
#define NROWS 100000   // B * N_NODES
#define BN_EPS 1e-5f
#define SCAN_BLOCKS 196   // ceil(50000 / 256)

typedef unsigned short ushort_t;
typedef unsigned int uint_t;
typedef __attribute__((ext_vector_type(8))) short bf16x8;   // MFMA A/B frag
typedef __attribute__((ext_vector_type(4))) float f32x4;    // MFMA C/D frag

// round-to-nearest-even fp32 -> bf16
__device__ inline ushort_t f2bf(float f) {
    uint_t x = __float_as_uint(f);
    x += 0x7fffu + ((x >> 16) & 1u);
    return (ushort_t)(x >> 16);
}
__device__ inline float4 bf4_to_f4(ushort4 u) {
    float4 f;
    f.x = __uint_as_float((uint_t)u.x << 16);
    f.y = __uint_as_float((uint_t)u.y << 16);
    f.z = __uint_as_float((uint_t)u.z << 16);
    f.w = __uint_as_float((uint_t)u.w << 16);
    return f;
}
// split-bf16: f = hi + lo with |err| ~ 2^-18 |f|
__device__ inline void split4(float4 v, bf16x8& hi, bf16x8& lo, int base) {
    float f[4] = {v.x, v.y, v.z, v.w};
    #pragma unroll
    for (int t = 0; t < 4; ++t) {
        ushort_t h = f2bf(f[t]);
        float fh = __uint_as_float((uint_t)h << 16);
        ushort_t l = f2bf(f[t] - fh);
        hi[base + t] = (short)h;
        lo[base + t] = (short)l;
    }
}

// ---------------- CSR build (per-destination buckets) ----------------

__global__ __launch_bounds__(256) void hist_kernel(const int* __restrict__ col,
                                                   int* __restrict__ cnt) {
    int e = blockIdx.x * 256 + threadIdx.x;
    if (e < N_EDGES) atomicAdd(&cnt[col[e]], 1);
}

__global__ __launch_bounds__(256) void scan_partials_sum(const int* __restrict__ cnt,
                                                         int* __restrict__ partials) {
    __shared__ int ws[4];
    int tid = threadIdx.x, lane = tid & 63, wid = tid >> 6;
    int i = blockIdx.x * 256 + tid;
    int v = (i < N_NODES) ? cnt[i] : 0;
    #pragma unroll
    for (int d = 32; d > 0; d >>= 1) v += __shfl_xor(v, d);
    if (lane == 0) ws[wid] = v;
    __syncthreads();
    if (tid == 0) partials[blockIdx.x] = ws[0] + ws[1] + ws[2] + ws[3];
}

__global__ __launch_bounds__(256) void scan_partials_scan(int* __restrict__ partials,
                                                          int* __restrict__ offsets) {
    __shared__ int ws[4];
    int tid = threadIdx.x, lane = tid & 63, wid = tid >> 6;
    int v = (tid < SCAN_BLOCKS) ? partials[tid] : 0;
    int x = v;
    #pragma unroll
    for (int d = 1; d < 64; d <<= 1) {
        int y = __shfl_up(x, d);
        if (lane >= d) x += y;
    }
    if (lane == 63) ws[wid] = x;
    __syncthreads();
    int woff = 0;
    for (int w = 0; w < wid; ++w) woff += ws[w];
    if (tid < SCAN_BLOCKS) partials[tid] = woff + x - v;   // exclusive
    if (tid == 255) offsets[N_NODES] = woff + x;           // grand total
}

__global__ __launch_bounds__(256) void scan_final(const int* __restrict__ cnt,
                                                  const int* __restrict__ partials,
                                                  int* __restrict__ offsets,
                                                  int* __restrict__ cursor) {
    __shared__ int ws[4];
    int tid = threadIdx.x, lane = tid & 63, wid = tid >> 6;
    int i = blockIdx.x * 256 + tid;
    int v = (i < N_NODES) ? cnt[i] : 0;
    int x = v;
    #pragma unroll
    for (int d = 1; d < 64; d <<= 1) {
        int y = __shfl_up(x, d);
        if (lane >= d) x += y;
    }
    if (lane == 63) ws[wid] = x;
    __syncthreads();
    int woff = 0;
    for (int w = 0; w < wid; ++w) woff += ws[w];
    if (i < N_NODES) {
        int off = partials[blockIdx.x] + woff + x - v;
        offsets[i] = off;
        cursor[i] = off;
    }
}

__global__ __launch_bounds__(256) void bucket_kernel(const int* __restrict__ row,
                                                     const int* __restrict__ col,
                                                     int* __restrict__ cursor,
                                                     int* __restrict__ srcbuf) {
    int e = blockIdx.x * 256 + threadIdx.x;
    if (e < N_EDGES) {
        int c = col[e];
        int p = atomicAdd(&cursor[c], 1);
        srcbuf[p] = row[e];
    }
}

// ---------------- W pre-transform + workspace zeroing ----------------
__global__ __launch_bounds__(256) void wsplit_kernel(const float* __restrict__ W1,
                                                     const float* __restrict__ W2,
                                                     ushort_t* __restrict__ wt,
                                                     int* __restrict__ cnt,
                                                     float* __restrict__ stats) {
    int idx = blockIdx.x * 256 + threadIdx.x;   // 0..32767
    for (int i = idx; i < N_NODES; i += 32768) cnt[i] = 0;
    if (idx < 512) stats[idx] = 0.f;
    int which = idx >> 14;
    int e = idx & 16383;                         // e = k*128 + n (coalesced read)
    int k = e >> 7, n = e & 127;
    float f = (which ? W2 : W1)[e];
    ushort_t h = f2bf(f);
    float fh = __uint_as_float((uint_t)h << 16);
    ushort_t l = f2bf(f - fh);
    size_t base = (size_t)which * 32768;
    wt[base + n * 128 + k] = h;                  // hi plane
    wt[base + 16384 + n * 128 + k] = l;          // lo plane
}

// ---------------- GEMM via split-bf16 MFMA (round-8 verified structure) ----------------
// W staged to LDS per 64-col half; BN coef computed in-block; C written to the
// interleaved sup layout [node][batch][128] bf16 (512B/node for the gather).
template <bool BN>
__global__ __launch_bounds__(256) void gemm_mfma(const float* __restrict__ A,
                                                 const ushort_t* __restrict__ wt,
                                                 const float* __restrict__ stats,
                                                 const float* __restrict__ gamma,
                                                 const float* __restrict__ beta,
                                                 ushort_t* __restrict__ C) {
    __shared__ short lds[32768];  // Ah[0,8192) Al[8192,16384) Wh[16384,24576) Wl[24576,32768)
    __shared__ float cs[256];     // scale[0:128], shift[128:256]
    int tid = threadIdx.x;
    long r0 = (long)blockIdx.x * 64;
    const float4* A4 = (const float4*)A;

    if (BN) {
        if (tid < 128) {
            float inv = 1.0f / (float)NROWS;
            float mean = stats[tid] * inv;
            float var = stats[128 + tid] * inv - mean * mean;
            float scale = gamma[tid] / sqrtf(var + BN_EPS);
            cs[tid] = scale;
            cs[128 + tid] = beta[tid] - mean * scale;
        }
        __syncthreads();
    }
    const float4* coef4 = (const float4*)cs;

    #pragma unroll
    for (int i = 0; i < 4; ++i) {
        int li = tid + i * 256;
        int r = li >> 4, j = li & 15;        // row 0..63, k-block 0..15
        long gr = r0 + r;
        float4 va = make_float4(0.f, 0.f, 0.f, 0.f), vb = va;
        if (gr < NROWS) { va = A4[gr * 32 + j * 2]; vb = A4[gr * 32 + j * 2 + 1]; }
        if (BN) {
            float4 sc = coef4[j * 2], sh = coef4[32 + j * 2];
            va.x = fmaxf(va.x * sc.x + sh.x, 0.f);
            va.y = fmaxf(va.y * sc.y + sh.y, 0.f);
            va.z = fmaxf(va.z * sc.z + sh.z, 0.f);
            va.w = fmaxf(va.w * sc.w + sh.w, 0.f);
            sc = coef4[j * 2 + 1]; sh = coef4[32 + j * 2 + 1];
            vb.x = fmaxf(vb.x * sc.x + sh.x, 0.f);
            vb.y = fmaxf(vb.y * sc.y + sh.y, 0.f);
            vb.z = fmaxf(vb.z * sc.z + sh.z, 0.f);
            vb.w = fmaxf(vb.w * sc.w + sh.w, 0.f);
        }
        bf16x8 vh, vl;
        split4(va, vh, vl, 0);
        split4(vb, vh, vl, 4);
        int off = r * 128 + ((j ^ (r & 15)) * 8);
        *(bf16x8*)&lds[off] = vh;
        *(bf16x8*)&lds[8192 + off] = vl;
    }

    int w = tid >> 6, l = tid & 63;
    int m = l & 15, q = l >> 4;
    for (int half = 0; half < 2; ++half) {
        __syncthreads();
        #pragma unroll
        for (int i = 0; i < 8; ++i) {
            int li = tid + i * 256;
            int p = li >> 10;                 // 0=hi 1=lo
            int rest = li & 1023;
            int nl = rest >> 4, j = rest & 15;
            bf16x8 v = *(const bf16x8*)&wt[(size_t)p * 16384 + (half * 64 + nl) * 128 + j * 8];
            *(bf16x8*)&lds[16384 + p * 8192 + nl * 128 + ((j ^ (nl & 15)) * 8)] = v;
        }
        __syncthreads();

        f32x4 acc[4] = {};
        #pragma unroll
        for (int s = 0; s < 4; ++s) {
            int x = (s * 4 + q) ^ m;
            int aoff = (w * 16 + m) * 128 + x * 8;
            bf16x8 ah = *(const bf16x8*)&lds[aoff];
            bf16x8 al = *(const bf16x8*)&lds[8192 + aoff];
            #pragma unroll
            for (int c = 0; c < 4; ++c) {
                int boff = 16384 + (c * 16 + m) * 128 + x * 8;
                bf16x8 bh = *(const bf16x8*)&lds[boff];
                bf16x8 bl = *(const bf16x8*)&lds[8192 + boff];
                acc[c] = __builtin_amdgcn_mfma_f32_16x16x32_bf16(al, bh, acc[c], 0, 0, 0);
                acc[c] = __builtin_amdgcn_mfma_f32_16x16x32_bf16(ah, bl, acc[c], 0, 0, 0);
                acc[c] = __builtin_amdgcn_mfma_f32_16x16x32_bf16(ah, bh, acc[c], 0, 0, 0);
            }
        }

        // write C (bf16, interleaved rows): row gr -> (node*2 + b)*128
        #pragma unroll
        for (int c = 0; c < 4; ++c) {
            #pragma unroll
            for (int r = 0; r < 4; ++r) {
                long gr = r0 + w * 16 + q * 4 + r;
                if (gr < NROWS) {
                    int b = gr >= N_NODES;
                    long node = gr - (long)b * N_NODES;
                    C[(node * 2 + b) * 128 + half * 64 + c * 16 + m] = f2bf(acc[c][r]);
                }
            }
        }
    }
}

// ---------------- Aggregate (verified hot loop; interleaved sup rows) ----------------
__global__ __launch_bounds__(256) void aggregate_bf16(const ushort_t* __restrict__ sup,
                                                      const int* __restrict__ offsets,
                                                      const int* __restrict__ srcbuf,
                                                      float* __restrict__ agg) {
    int lane = threadIdx.x & 63;
    int wid = threadIdx.x >> 6;
    int node = blockIdx.x * 4 + wid;        // 12500*4 = 50000 exactly
    int s = lane >> 5;       // half-wave id
    int l32 = lane & 31;
    int beg = offsets[node], end = offsets[node + 1];
    const ushort4* sb = (const ushort4*)sup;   // row r: [r*64, r*64+32)=batch0, +32..64)=batch1
    float4 a0 = make_float4(0.f, 0.f, 0.f, 0.f);
    float4 a1 = make_float4(0.f, 0.f, 0.f, 0.f);
    for (int i = beg; i < end; i += 64) {
        int m = end - i; if (m > 64) m = 64;
        int idx = (i + lane < end) ? srcbuf[i + lane] : 0;  // coalesced index load
        int tmax = (m + 1) >> 1;
        #pragma unroll 2
        for (int t = 0; t < tmax; ++t) {
            int j = 2 * t + s;
            int r = __shfl(idx, j & 63);
            ushort4 u0 = sb[(size_t)r * 64 + l32];        // batch 0 half-row
            ushort4 u1 = sb[(size_t)r * 64 + 32 + l32];   // batch 1 half-row
            if (j < m) {
                float4 f0 = bf4_to_f4(u0);
                float4 f1 = bf4_to_f4(u1);
                a0.x += f0.x; a0.y += f0.y; a0.z += f0.z; a0.w += f0.w;
                a1.x += f1.x; a1.y += f1.y; a1.z += f1.z; a1.w += f1.w;
            }
        }
    }
    a0.x += __shfl_xor(a0.x, 32); a0.y += __shfl_xor(a0.y, 32);
    a0.z += __shfl_xor(a0.z, 32); a0.w += __shfl_xor(a0.w, 32);
    a1.x += __shfl_xor(a1.x, 32); a1.y += __shfl_xor(a1.y, 32);
    a1.z += __shfl_xor(a1.z, 32); a1.w += __shfl_xor(a1.w, 32);
    float4* ag = (float4*)agg;
    if (s == 0) ag[(size_t)node * 32 + l32] = a0;                       // batch 0 row
    else        ag[(size_t)(N_NODES + node) * 32 + l32] = a1;           // batch 1 row
}

// ---------------- BatchNorm stats (over raw agg) ----------------

__global__ __launch_bounds__(256) void bn_stats_kernel(const float* __restrict__ h,
                                                       float* __restrict__ stats) {
    __shared__ float ls[256], ls2[256];
    int tid = threadIdx.x;
    int f = tid & 127, half = tid >> 7;
    float s = 0.f, s2 = 0.f;
    for (int row = blockIdx.x * 2 + half; row < NROWS; row += gridDim.x * 2) {
        float v = h[(size_t)row * FDIM + f];
        s += v; s2 += v * v;
    }
    ls[tid] = s; ls2[tid] = s2;
    __syncthreads();
    if (tid < 128) {
        atomicAdd(&stats[f], ls[tid] + ls[tid + 128]);
        atomicAdd(&stats[128 + f], ls2[tid] + ls2[tid + 128]);
    }
}

// ---------------- Layer 3: fused BN+ReLU GEMV (coef in-block) + CSR gather ----------------
__global__ __launch_bounds__(256) void gemv_bn_kernel(const float* __restrict__ h,
                                                      const float* __restrict__ stats,
                                                      const float* __restrict__ gamma,
                                                      const float* __restrict__ beta,
                                                      const float* __restrict__ W3,
                                                      float* __restrict__ sup3) {
    __shared__ float cs[256];
    int tid = threadIdx.x;
    if (tid < 128) {
        float inv = 1.0f / (float)NROWS;
        float mean = stats[tid] * inv;
        float var = stats[128 + tid] * inv - mean * mean;
        float scale = gamma[tid] / sqrtf(var + BN_EPS);
        cs[tid] = scale;
        cs[128 + tid] = beta[tid] - mean * scale;
    }
    __syncthreads();
    int lane = tid & 63, wid = tid >> 6;
    float2 w  = ((const float2*)W3)[lane];
    float2 sc = ((const float2*)cs)[lane];
    float2 sh = ((const float2*)(cs + 128))[lane];
    #pragma unroll
    for (int r = 0; r < 4; ++r) {
        long gw = (long)blockIdx.x * 16 + wid * 4 + r;   // 6250*16 = 100000 exactly
        float2 v = ((const float2*)h)[(size_t)gw * 64 + lane];
        v.x = fmaxf(v.x * sc.x + sh.x, 0.f);
        v.y = fmaxf(v.y * sc.y + sh.y, 0.f);
        float s = v.x * w.x + v.y * w.y;
        #pragma unroll
        for (int d = 32; d > 0; d >>= 1) s += __shfl_xor(s, d);
        if (lane == 0) sup3[gw] = s;
    }
}

// out[b,n] = b3 + sum over CSR in-edges of sup3[b, src].
__global__ __launch_bounds__(256) void gather_out_kernel(const int* __restrict__ offsets,
                                                         const int* __restrict__ srcbuf,
                                                         const float* __restrict__ sup3,
                                                         const float* __restrict__ b3,
                                                         float* __restrict__ out) {
    int n = blockIdx.x * 256 + threadIdx.x;
    if (n >= N_NODES) return;
    int beg = offsets[n], end = offsets[n + 1];
    float s0 = 0.f, s1 = 0.f;
    for (int i = beg; i < end; ++i) {
        int r = srcbuf[i];
        s0 += sup3[r];
        s1 += sup3[N_NODES + r];
    }
    float b = b3[0];
    out[n] = s0 + b;
    out[N_NODES + n] = s1 + b;
}

// ---------------- launch ----------------

extern "C" void kernel_launch(void* const* d_in, const int* in_sizes, int n_in,
                              void* d_out, int out_size, void* d_ws, size_t ws_size,
                              hipStream_t stream) {
    const float* x      = (const float*)d_in[0];
    const int*   ei     = (const int*)d_in[1];
    const float* W1     = (const float*)d_in[2];
    // d_in[3] = b1: per-feature bias before BN cancels exactly (shifts mean identically)
    const float* W2     = (const float*)d_in[4];
    // d_in[5] = b2: same cancellation
    const float* W3     = (const float*)d_in[6];
    const float* b3     = (const float*)d_in[7];
    const float* gamma1 = (const float*)d_in[8];
    const float* beta1  = (const float*)d_in[9];
    const float* gamma2 = (const float*)d_in[10];
    const float* beta2  = (const float*)d_in[11];
    const int* rowp = ei;             // edge_index[0]
    const int* colp = ei + N_EDGES;   // edge_index[1]

    ushort_t* sup   = (ushort_t*)d_ws;              // 12.8M bf16 (25.6 MB), [node][batch][128]
    float* agg      = (float*)(sup + 12800000);     // 12.8M floats (51.2 MB), [b*N+node][128]
    float* sup3     = agg + 12800000;               // 100k floats
    ushort_t* wt    = (ushort_t*)(sup3 + 100000);   // 65536 ushorts: W1/W2 split planes
    float* stats    = (float*)(wt + 65536);         // 512 floats
    int*   cnt      = (int*)(stats + 512);          // 50000
    int*   offsets  = cnt + N_NODES;                // 50001
    int*   cursor   = offsets + N_NODES + 1;        // 50000
    int*   srcbuf   = cursor + N_NODES;             // 800000
    int*   scanp    = srcbuf + N_EDGES;             // 196
    float* out      = (float*)d_out;

    // W split/transpose + cnt/stats zeroing, then CSR build
    wsplit_kernel     <<<128,         256, 0, stream>>>(W1, W2, wt, cnt, stats);
    hist_kernel       <<<3125,        256, 0, stream>>>(colp, cnt);
    scan_partials_sum <<<SCAN_BLOCKS, 256, 0, stream>>>(cnt, scanp);
    scan_partials_scan<<<1,           256, 0, stream>>>(scanp, offsets);
    scan_final        <<<SCAN_BLOCKS, 256, 0, stream>>>(cnt, scanp, offsets, cursor);
    bucket_kernel     <<<3125,        256, 0, stream>>>(rowp, colp, cursor, srcbuf);

    // layer 1: sup = x@W1 (split-bf16 MFMA), agg = A·sup, stats
    gemm_mfma<false><<<1563,  256, 0, stream>>>(x, wt, nullptr, nullptr, nullptr, sup);
    aggregate_bf16  <<<12500, 256, 0, stream>>>(sup, offsets, srcbuf, agg);
    bn_stats_kernel <<<512,   256, 0, stream>>>(agg, stats);

    // layer 2: sup = relu(bn1(agg))@W2 (coef computed in-block), agg = A·sup, stats
    gemm_mfma<true> <<<1563,  256, 0, stream>>>(agg, wt + 32768, stats, gamma1, beta1, sup);
    aggregate_bf16  <<<12500, 256, 0, stream>>>(sup, offsets, srcbuf, agg);
    bn_stats_kernel <<<512,   256, 0, stream>>>(agg, stats + 256);

    // layer 3: sup3 = relu(bn2(agg))@W3 (coef in-block), out = A·sup3 + b3 (CSR gather)
    gemv_bn_kernel   <<<6250, 256, 0, stream>>>(agg, stats + 256, gamma2, beta2, W3, sup3);
    gather_out_kernel<<<SCAN_BLOCKS, 256, 0, stream>>>(offsets, srcbuf, sup3, b3, out);
}